// Round 10
// baseline (383.525 us; speedup 1.0000x reference)
//
#include <hip/hip_runtime.h>
#include <stdint.h>

#define BSZ 64
#define SEQ 197
#define EMB 768
#define NH  12
#define HD  64
#define M_TOK (BSZ*SEQ)      // 12608 token rows
#define SHD (SEQ*HD)         // 12608 elements per (b,h) head matrix

using bf16x8 = __attribute__((ext_vector_type(8))) short;
using f32x4  = __attribute__((ext_vector_type(4))) float;

__device__ __forceinline__ float bflo(uint32_t u) { return __uint_as_float(u << 16); }
__device__ __forceinline__ uint16_t f2bf(float f) {
    uint32_t u = __float_as_uint(f);
    u += 0x7fffu + ((u >> 16) & 1u);   // RNE
    return (uint16_t)(u >> 16);
}

// ---------------------------------------------------------------- convert
struct CvtJob { const float* src; uint16_t* dst; int n8; };
struct CvtJobs { CvtJob j[9]; };

__global__ __launch_bounds__(256) void convert_kernel(CvtJobs jobs)
{
    int idx = blockIdx.x * 256 + threadIdx.x;
    #pragma unroll
    for (int r = 0; r < 9; ++r) {
        const int n8 = jobs.j[r].n8;
        if (idx < n8) {
            const uint4* s4 = (const uint4*)(jobs.j[r].src + (size_t)idx * 8);
            uint4 a = s4[0], b = s4[1];
            uint4 w;
            w.x = (uint32_t)f2bf(__uint_as_float(a.x)) | ((uint32_t)f2bf(__uint_as_float(a.y)) << 16);
            w.y = (uint32_t)f2bf(__uint_as_float(a.z)) | ((uint32_t)f2bf(__uint_as_float(a.w)) << 16);
            w.z = (uint32_t)f2bf(__uint_as_float(b.x)) | ((uint32_t)f2bf(__uint_as_float(b.y)) << 16);
            w.w = (uint32_t)f2bf(__uint_as_float(b.z)) | ((uint32_t)f2bf(__uint_as_float(b.w)) << 16);
            *(uint4*)(jobs.j[r].dst + (size_t)idx * 8) = w;
            return;
        }
        idx -= n8;
    }
}

// ---------------------------------------------------------------- GEMM
struct GemmPtrs {
    const uint16_t* W[3];
    const uint16_t* b[3];
    void*           out[3];
};

// C[m][n] = sum_k A[m][k]*W[n][k] + bias[n]  (NT, bf16 in, fp32 acc)
// Round-10: BARRIER-FREE. r5-r9 post-mortem: any K-loop with
// vmcnt(0)->s_barrier pays ~5000cy/iter regardless of staging structure
// (per-block wall ~120Kcy invariant across 5 variants). So: no LDS, no
// barriers — each wave computes an independent 64x64 tile, A and B fragments
// loaded per-lane direct from global (NT 16B/lane pattern; correctness
// validated by attn's K loads since r5). Latency hiding is statistical
// across waves; floor becomes L2 BW (~40us QKV) not the barrier chain.
// Block = 2x2 waves (128x128 region) for L1 reuse of A/B rows.
// per_m = n-tiles(128) per m-tile: QKV 18 (z = nt/6), proj 6 (z=0).
__global__ __launch_bounds__(256, 3) void gemm_bias_nt(const uint16_t* __restrict__ A,
                                                       GemmPtrs p, int M,
                                                       int total, int per_m, int outf32)
{
    // ---- XCD swizzle: same-m-tile blocks land on one XCD ----
    const int flat  = blockIdx.x;
    const int xcd   = flat & 7;
    const int local = flat >> 3;
    const int cbk = total >> 3, r8 = total & 7;
    const int start = xcd * cbk + (xcd < r8 ? xcd : r8);
    const int wid = start + local;
    const int m_idx = wid / per_m;
    const int nt    = wid - m_idx * per_m;
    const int z     = nt / 6;            // per_m=6 -> 0
    const int n0    = (nt - z * 6) * 128;

    const uint16_t* __restrict__ W    = p.W[z];
    const uint16_t* __restrict__ bias = p.b[z];

    const int m0   = m_idx * 128;
    const int tid  = threadIdx.x;
    const int lane = tid & 63;
    const int wave = tid >> 6;
    const int wr = wave >> 1, wc = wave & 1;   // 2x2 waves: 64m x 64n each
    const int l15 = lane & 15;
    const int kq  = lane >> 4;

    // ---- per-lane fragment base pointers (A and B both NT row-major) ----
    const uint16_t* ap[4];
    const uint16_t* bp[4];
    #pragma unroll
    for (int i = 0; i < 4; ++i) {
        int m = m0 + 64 * wr + 16 * i + l15; if (m >= M) m = M - 1;
        ap[i] = A + (size_t)m * EMB + kq * 8;
    }
    #pragma unroll
    for (int j = 0; j < 4; ++j) {
        int n = n0 + 64 * wc + 16 * j + l15;
        bp[j] = W + (size_t)n * EMB + kq * 8;
    }

    f32x4 acc[4][4] = {};

    for (int k0 = 0; k0 < EMB; k0 += 32) {
        bf16x8 af[4], bfr[4];
        #pragma unroll
        for (int i = 0; i < 4; ++i) af[i]  = *(const bf16x8*)(ap[i] + k0);
        #pragma unroll
        for (int j = 0; j < 4; ++j) bfr[j] = *(const bf16x8*)(bp[j] + k0);

        #pragma unroll
        for (int i = 0; i < 4; ++i)
            #pragma unroll
            for (int j = 0; j < 4; ++j)
                acc[i][j] = __builtin_amdgcn_mfma_f32_16x16x32_bf16(af[i], bfr[j], acc[i][j], 0, 0, 0);
    }

    // C/D: col = lane&15, row = (lane>>4)*4 + reg
    const int kq4 = kq * 4;
    #pragma unroll
    for (int j = 0; j < 4; ++j) {
        int n = n0 + 64 * wc + 16 * j + l15;
        float bv = bflo((uint32_t)bias[n]);
        #pragma unroll
        for (int i = 0; i < 4; ++i) {
            #pragma unroll
            for (int r = 0; r < 4; ++r) {
                int m = m0 + 64 * wr + 16 * i + kq4 + r;
                if (m < M) {
                    float v = acc[i][j][r] + bv;
                    if (outf32) ((float*)p.out[z])[(size_t)m * EMB + n] = v;
                    else        ((uint16_t*)p.out[z])[(size_t)m * EMB + n] = f2bf(v);
                }
            }
        }
    }
}

// ---------------------------------------------------------------- attention (MFMA)
#define RV 264   // sVt row stride (keys)
#define RP 72    // sP row stride
__global__ __launch_bounds__(256) void attn_kernel(const uint16_t* __restrict__ Qg,
                                                   const uint16_t* __restrict__ Kg,
                                                   const uint16_t* __restrict__ Vg,
                                                   uint16_t* __restrict__ Og)
{
    __shared__ __align__(16) uint16_t sVt[HD * RV];
    __shared__ __align__(16) uint16_t sP[4][64 * RP];

    const int bh  = blockIdx.x;
    const size_t base = (size_t)bh * SHD;
    const int tid  = threadIdx.x;
    const int lane = tid & 63;
    const int w    = tid >> 6;
    const int l15  = lane & 15;
    const int kq   = lane >> 4;
    uint16_t* sPw = sP[w];

    {
        int r = tid >> 2, t4 = tid & 3;
        for (int c = SEQ + t4; c < RV; c += 4) sVt[r * RV + c] = 0;
    }
    for (int idx = tid; idx < SHD / 8; idx += 256) {
        int key = idx >> 3, dc = idx & 7;
        uint4 v = ((const uint4*)(Vg + base))[idx];
        uint16_t e[8];
        *(uint4*)e = v;
        #pragma unroll
        for (int j = 0; j < 8; ++j) sVt[(dc * 8 + j) * RV + key] = e[j];
    }

    bf16x8 aq[4][2];
    #pragma unroll
    for (int mi = 0; mi < 4; ++mi) {
        int m = 64 * w + 16 * mi + l15; if (m >= SEQ) m = SEQ - 1;
        const uint16_t* qp = Qg + base + (size_t)m * HD + kq * 8;
        aq[mi][0] = *(const bf16x8*)(qp);
        aq[mi][1] = *(const bf16x8*)(qp + 32);
    }

    bf16x8 ones;
    #pragma unroll
    for (int j = 0; j < 8; ++j) ones[j] = (short)0x3F80;

    f32x4 oacc[4][4] = {};
    f32x4 lacc[4]    = {};

    __syncthreads();   // sVt ready

    for (int c = 0; c < 4; ++c) {
        bf16x8 bk[4][2];
        #pragma unroll
        for (int ni = 0; ni < 4; ++ni) {
            int key = 64 * c + 16 * ni + l15; if (key >= SEQ) key = SEQ - 1;
            const uint16_t* kp = Kg + base + (size_t)key * HD + kq * 8;
            bk[ni][0] = *(const bf16x8*)(kp);
            bk[ni][1] = *(const bf16x8*)(kp + 32);
        }
        #pragma unroll
        for (int mi = 0; mi < 4; ++mi) {
            #pragma unroll
            for (int ni = 0; ni < 4; ++ni) {
                f32x4 s = {};
                s = __builtin_amdgcn_mfma_f32_16x16x32_bf16(aq[mi][0], bk[ni][0], s, 0, 0, 0);
                s = __builtin_amdgcn_mfma_f32_16x16x32_bf16(aq[mi][1], bk[ni][1], s, 0, 0, 0);
                int col = 16 * ni + l15;
                int key = 64 * c + col;
                #pragma unroll
                for (int r = 0; r < 4; ++r) {
                    float pv = (key < SEQ) ? __expf(fminf(s[r], 80.f)) : 0.f;
                    sPw[(16 * mi + kq * 4 + r) * RP + col] = f2bf(pv);
                }
            }
        }

        bf16x8 bv[2][4];
        #pragma unroll
        for (int kk = 0; kk < 2; ++kk)
            #pragma unroll
            for (int ni = 0; ni < 4; ++ni)
                bv[kk][ni] = *(const bf16x8*)(sVt + (16 * ni + l15) * RV + c * 64 + kk * 32 + kq * 8);

        #pragma unroll
        for (int mi = 0; mi < 4; ++mi) {
            #pragma unroll
            for (int kk = 0; kk < 2; ++kk) {
                bf16x8 ap = *(const bf16x8*)(sPw + (16 * mi + l15) * RP + kk * 32 + kq * 8);
                lacc[mi] = __builtin_amdgcn_mfma_f32_16x16x32_bf16(ap, ones, lacc[mi], 0, 0, 0);
                #pragma unroll
                for (int ni = 0; ni < 4; ++ni)
                    oacc[mi][ni] = __builtin_amdgcn_mfma_f32_16x16x32_bf16(ap, bv[kk][ni], oacc[mi][ni], 0, 0, 0);
            }
        }
    }

    #pragma unroll
    for (int mi = 0; mi < 4; ++mi) {
        #pragma unroll
        for (int r = 0; r < 4; ++r) {
            int m = 64 * w + 16 * mi + kq * 4 + r;
            if (m < SEQ) {
                float scale = 1.f / (lacc[mi][r] * 27.712812921102035f);
                #pragma unroll
                for (int ni = 0; ni < 4; ++ni)
                    Og[base + (size_t)m * HD + 16 * ni + l15] = f2bf(oacc[mi][ni][r] * scale);
            }
        }
    }
}

// ---------------------------------------------------------------- launch
extern "C" void kernel_launch(void* const* d_in, const int* in_sizes, int n_in,
                              void* d_out, int out_size, void* d_ws, size_t ws_size,
                              hipStream_t stream)
{
    const size_t NX = (size_t)M_TOK * EMB;
    const size_t NW = (size_t)EMB * EMB;
    const size_t NB = EMB;

    uint16_t* xbf = (uint16_t*)d_ws;
    uint16_t* Wbf[4]; uint16_t* bbf[4];
    uint16_t* cur = xbf + NX;
    for (int i = 0; i < 4; ++i) { Wbf[i] = cur; cur += NW; }
    for (int i = 0; i < 4; ++i) { bbf[i] = cur; cur += NB; }
    uint16_t* Qw = cur;
    uint16_t* Kw = Qw + NX;
    uint16_t* Vw = Kw + NX;

    const size_t need_primary  = 2 * (NX + 4 * NW + 4 * NB + 3 * NX);
    const size_t need_fallback = need_primary - 2 * NX;
    if (ws_size < need_fallback) return;
    if (ws_size < need_primary) Vw = (uint16_t*)d_out;

    CvtJobs jobs;
    jobs.j[0] = { (const float*)d_in[0], xbf,    (int)(NX / 8) };
    jobs.j[1] = { (const float*)d_in[1], Wbf[0], (int)(NW / 8) };
    jobs.j[2] = { (const float*)d_in[3], Wbf[1], (int)(NW / 8) };
    jobs.j[3] = { (const float*)d_in[5], Wbf[2], (int)(NW / 8) };
    jobs.j[4] = { (const float*)d_in[7], Wbf[3], (int)(NW / 8) };
    jobs.j[5] = { (const float*)d_in[2], bbf[0], (int)(NB / 8) };
    jobs.j[6] = { (const float*)d_in[4], bbf[1], (int)(NB / 8) };
    jobs.j[7] = { (const float*)d_in[6], bbf[2], (int)(NB / 8) };
    jobs.j[8] = { (const float*)d_in[8], bbf[3], (int)(NB / 8) };
    const int total8 = (int)((NX + 4 * NW + 4 * NB) / 8);
    convert_kernel<<<(total8 + 255) / 256, 256, 0, stream>>>(jobs);

    const int MT = (M_TOK + 127) / 128;   // 99 m-tiles

    GemmPtrs qkv;
    qkv.W[0] = Wbf[0]; qkv.W[1] = Wbf[1]; qkv.W[2] = Wbf[2];
    qkv.b[0] = bbf[0]; qkv.b[1] = bbf[1]; qkv.b[2] = bbf[2];
    qkv.out[0] = Qw; qkv.out[1] = Kw; qkv.out[2] = Vw;
    const int tot1 = MT * 18;             // 6 n-tiles x 3 weight sets
    gemm_bias_nt<<<tot1, 256, 0, stream>>>(xbf, qkv, M_TOK, tot1, 18, 0);

    attn_kernel<<<dim3(BSZ * NH), 256, 0, stream>>>(Qw, Kw, Vw, Qw);

    GemmPtrs pr;
    pr.W[0] = pr.W[1] = pr.W[2] = Wbf[3];
    pr.b[0] = pr.b[1] = pr.b[2] = bbf[3];
    pr.out[0] = pr.out[1] = pr.out[2] = d_out;
    const int tot2 = MT * 6;              // 6 n-tiles
    gemm_bias_nt<<<tot2, 256, 0, stream>>>(Qw, pr, M_TOK, tot2, 6, 1);
}

// Round 11
// 255.701 us; speedup vs baseline: 1.4999x; 1.4999x over previous
//
#include <hip/hip_runtime.h>
#include <stdint.h>

#define BSZ 64
#define SEQ 197
#define EMB 768
#define NH  12
#define HD  64
#define M_TOK (BSZ*SEQ)      // 12608 token rows
#define SHD (SEQ*HD)         // 12608 elements per (b,h) head matrix

using bf16x8 = __attribute__((ext_vector_type(8))) short;
using f32x4  = __attribute__((ext_vector_type(4))) float;

__device__ __forceinline__ float bflo(uint32_t u) { return __uint_as_float(u << 16); }
__device__ __forceinline__ uint16_t f2bf(float f) {
    uint32_t u = __float_as_uint(f);
    u += 0x7fffu + ((u >> 16) & 1u);   // RNE
    return (uint16_t)(u >> 16);
}

// ---------------------------------------------------------------- convert
struct CvtJob { const float* src; uint16_t* dst; int n8; };
struct CvtJobs { CvtJob j[9]; };

__global__ __launch_bounds__(256) void convert_kernel(CvtJobs jobs)
{
    int idx = blockIdx.x * 256 + threadIdx.x;
    #pragma unroll
    for (int r = 0; r < 9; ++r) {
        const int n8 = jobs.j[r].n8;
        if (idx < n8) {
            const uint4* s4 = (const uint4*)(jobs.j[r].src + (size_t)idx * 8);
            uint4 a = s4[0], b = s4[1];
            uint4 w;
            w.x = (uint32_t)f2bf(__uint_as_float(a.x)) | ((uint32_t)f2bf(__uint_as_float(a.y)) << 16);
            w.y = (uint32_t)f2bf(__uint_as_float(a.z)) | ((uint32_t)f2bf(__uint_as_float(a.w)) << 16);
            w.z = (uint32_t)f2bf(__uint_as_float(b.x)) | ((uint32_t)f2bf(__uint_as_float(b.y)) << 16);
            w.w = (uint32_t)f2bf(__uint_as_float(b.z)) | ((uint32_t)f2bf(__uint_as_float(b.w)) << 16);
            *(uint4*)(jobs.j[r].dst + (size_t)idx * 8) = w;
            return;
        }
        idx -= n8;
    }
}

// ---------------------------------------------------------------- GEMM
struct GemmPtrs {
    const uint16_t* W[3];
    const uint16_t* b[3];
    void*           out[3];
};

// C[m][n] = sum_k A[m][k]*W[n][k] + bias[n]  (NT, bf16 in, fp32 acc)
// Round-11: BK=128 single-buffer — 6 K-iterations instead of 24. r6-r10
// evidence: per-iteration wall (~5000cy: latency chain + barriers) is
// invariant to everything inside the iteration; so cut iteration COUNT 4x.
// A+B tiles 64KB LDS, 2 blocks/CU (r8 residency — no occupancy loss),
// 64 MFMA/wave/iter, 12 barriers/block (was 48).
// LDS conflict fix at 256B row stride: store k-chunk kc of row r at slot
// kc^(r&15) (applied on DMA *source* addr; dst stays base+lane*16 per the
// global_load_lds contract), reader XORs back with l15 -> 2-way, free.
// per_m = n-tiles(128) per m-tile: QKV 18 (z=nt/6), proj 6 (z=0).
__global__ __launch_bounds__(256, 2) void gemm_bias_nt(const uint16_t* __restrict__ A,
                                                       GemmPtrs p, int M,
                                                       int total, int per_m, int outf32)
{
    __shared__ __align__(16) uint16_t sA[128 * 128];   // 32 KB
    __shared__ __align__(16) uint16_t sB[128 * 128];   // 32 KB

    // ---- XCD swizzle: same-m-tile blocks land on one XCD ----
    const int flat  = blockIdx.x;
    const int xcd   = flat & 7;
    const int local = flat >> 3;
    const int cbk = total >> 3, r8 = total & 7;
    const int start = xcd * cbk + (xcd < r8 ? xcd : r8);
    const int wid = start + local;
    const int m_idx = wid / per_m;
    const int nt    = wid - m_idx * per_m;
    const int z     = nt / 6;            // per_m=6 -> 0
    const int n0    = (nt - z * 6) * 128;

    const uint16_t* __restrict__ W    = p.W[z];
    const uint16_t* __restrict__ bias = p.b[z];

    const int m0   = m_idx * 128;
    const int tid  = threadIdx.x;
    const int lane = tid & 63;
    const int wave = tid >> 6;
    const int wr = wave >> 1, wc = wave & 1;   // 2x2 waves: 64m x 64n each
    const int l15 = lane & 15;
    const int kq  = lane >> 4;

    // ---- staging pointers: 2048 chunks of 16B per tile, 8/thread ----
    // chunk ch = tid + 256*q: row rt = ch>>4, k-chunk kc = ch&15.
    // source k-offset XOR-swizzled: elems (kc ^ (rt&15))*8.
    const uint16_t* apq[8];
    const uint16_t* bpq[8];
    #pragma unroll
    for (int q = 0; q < 8; ++q) {
        int ch = tid + 256 * q;
        int rt = ch >> 4, kc = ch & 15;
        int ks = (kc ^ (rt & 15)) * 8;
        int ga = m0 + rt; if (ga >= M) ga = M - 1;
        apq[q] = A + (size_t)ga * EMB + ks;
        bpq[q] = W + (size_t)(n0 + rt) * EMB + ks;
    }

    f32x4 acc[4][4] = {};

    const int NIT = EMB / 128;   // 6
    for (int it = 0; it < NIT; ++it) {
        if (it > 0) {
            asm volatile("s_waitcnt lgkmcnt(0)" ::: "memory");  // prev reads done
            __builtin_amdgcn_s_barrier();                       // before overwrite
            asm volatile("" ::: "memory");
        }
        const int k0 = it * 128;
        #pragma unroll
        for (int q = 0; q < 8; ++q) {
            int ch8 = (tid + 256 * q) * 8;
            __builtin_amdgcn_global_load_lds(
                (const __attribute__((address_space(1))) void*)(apq[q] + k0),
                (__attribute__((address_space(3))) void*)(sA + ch8), 16, 0, 0);
            __builtin_amdgcn_global_load_lds(
                (const __attribute__((address_space(1))) void*)(bpq[q] + k0),
                (__attribute__((address_space(3))) void*)(sB + ch8), 16, 0, 0);
        }
        asm volatile("s_waitcnt vmcnt(0)" ::: "memory");
        __builtin_amdgcn_s_barrier();
        asm volatile("" ::: "memory");

        #pragma unroll
        for (int s = 0; s < 4; ++s) {
            const int cs = ((s * 4 + kq)) ;                 // logical k-chunk
            bf16x8 af[4], bfr[4];
            #pragma unroll
            for (int i = 0; i < 4; ++i) {
                int row = 64 * wr + 16 * i + l15;
                af[i] = *(const bf16x8*)(sA + row * 128 + (cs ^ l15) * 8);
            }
            #pragma unroll
            for (int j = 0; j < 4; ++j) {
                int row = 64 * wc + 16 * j + l15;
                bfr[j] = *(const bf16x8*)(sB + row * 128 + (cs ^ l15) * 8);
            }
            #pragma unroll
            for (int i = 0; i < 4; ++i)
                #pragma unroll
                for (int j = 0; j < 4; ++j)
                    acc[i][j] = __builtin_amdgcn_mfma_f32_16x16x32_bf16(af[i], bfr[j], acc[i][j], 0, 0, 0);
        }
    }

    // C/D: col = lane&15, row = (lane>>4)*4 + reg
    const int kq4 = kq * 4;
    #pragma unroll
    for (int j = 0; j < 4; ++j) {
        int n = n0 + 64 * wc + 16 * j + l15;
        float bv = bflo((uint32_t)bias[n]);
        #pragma unroll
        for (int i = 0; i < 4; ++i) {
            #pragma unroll
            for (int r = 0; r < 4; ++r) {
                int m = m0 + 64 * wr + 16 * i + kq4 + r;
                if (m < M) {
                    float v = acc[i][j][r] + bv;
                    if (outf32) ((float*)p.out[z])[(size_t)m * EMB + n] = v;
                    else        ((uint16_t*)p.out[z])[(size_t)m * EMB + n] = f2bf(v);
                }
            }
        }
    }
}

// ---------------------------------------------------------------- attention (MFMA)
#define RV 264   // sVt row stride (keys)
#define RP 72    // sP row stride
__global__ __launch_bounds__(256) void attn_kernel(const uint16_t* __restrict__ Qg,
                                                   const uint16_t* __restrict__ Kg,
                                                   const uint16_t* __restrict__ Vg,
                                                   uint16_t* __restrict__ Og)
{
    __shared__ __align__(16) uint16_t sVt[HD * RV];
    __shared__ __align__(16) uint16_t sP[4][64 * RP];

    const int bh  = blockIdx.x;
    const size_t base = (size_t)bh * SHD;
    const int tid  = threadIdx.x;
    const int lane = tid & 63;
    const int w    = tid >> 6;
    const int l15  = lane & 15;
    const int kq   = lane >> 4;
    uint16_t* sPw = sP[w];

    {
        int r = tid >> 2, t4 = tid & 3;
        for (int c = SEQ + t4; c < RV; c += 4) sVt[r * RV + c] = 0;
    }
    for (int idx = tid; idx < SHD / 8; idx += 256) {
        int key = idx >> 3, dc = idx & 7;
        uint4 v = ((const uint4*)(Vg + base))[idx];
        uint16_t e[8];
        *(uint4*)e = v;
        #pragma unroll
        for (int j = 0; j < 8; ++j) sVt[(dc * 8 + j) * RV + key] = e[j];
    }

    bf16x8 aq[4][2];
    #pragma unroll
    for (int mi = 0; mi < 4; ++mi) {
        int m = 64 * w + 16 * mi + l15; if (m >= SEQ) m = SEQ - 1;
        const uint16_t* qp = Qg + base + (size_t)m * HD + kq * 8;
        aq[mi][0] = *(const bf16x8*)(qp);
        aq[mi][1] = *(const bf16x8*)(qp + 32);
    }

    bf16x8 ones;
    #pragma unroll
    for (int j = 0; j < 8; ++j) ones[j] = (short)0x3F80;

    f32x4 oacc[4][4] = {};
    f32x4 lacc[4]    = {};

    __syncthreads();   // sVt ready

    for (int c = 0; c < 4; ++c) {
        bf16x8 bk[4][2];
        #pragma unroll
        for (int ni = 0; ni < 4; ++ni) {
            int key = 64 * c + 16 * ni + l15; if (key >= SEQ) key = SEQ - 1;
            const uint16_t* kp = Kg + base + (size_t)key * HD + kq * 8;
            bk[ni][0] = *(const bf16x8*)(kp);
            bk[ni][1] = *(const bf16x8*)(kp + 32);
        }
        #pragma unroll
        for (int mi = 0; mi < 4; ++mi) {
            #pragma unroll
            for (int ni = 0; ni < 4; ++ni) {
                f32x4 s = {};
                s = __builtin_amdgcn_mfma_f32_16x16x32_bf16(aq[mi][0], bk[ni][0], s, 0, 0, 0);
                s = __builtin_amdgcn_mfma_f32_16x16x32_bf16(aq[mi][1], bk[ni][1], s, 0, 0, 0);
                int col = 16 * ni + l15;
                int key = 64 * c + col;
                #pragma unroll
                for (int r = 0; r < 4; ++r) {
                    float pv = (key < SEQ) ? __expf(fminf(s[r], 80.f)) : 0.f;
                    sPw[(16 * mi + kq * 4 + r) * RP + col] = f2bf(pv);
                }
            }
        }

        bf16x8 bv[2][4];
        #pragma unroll
        for (int kk = 0; kk < 2; ++kk)
            #pragma unroll
            for (int ni = 0; ni < 4; ++ni)
                bv[kk][ni] = *(const bf16x8*)(sVt + (16 * ni + l15) * RV + c * 64 + kk * 32 + kq * 8);

        #pragma unroll
        for (int mi = 0; mi < 4; ++mi) {
            #pragma unroll
            for (int kk = 0; kk < 2; ++kk) {
                bf16x8 ap = *(const bf16x8*)(sPw + (16 * mi + l15) * RP + kk * 32 + kq * 8);
                lacc[mi] = __builtin_amdgcn_mfma_f32_16x16x32_bf16(ap, ones, lacc[mi], 0, 0, 0);
                #pragma unroll
                for (int ni = 0; ni < 4; ++ni)
                    oacc[mi][ni] = __builtin_amdgcn_mfma_f32_16x16x32_bf16(ap, bv[kk][ni], oacc[mi][ni], 0, 0, 0);
            }
        }
    }

    #pragma unroll
    for (int mi = 0; mi < 4; ++mi) {
        #pragma unroll
        for (int r = 0; r < 4; ++r) {
            int m = 64 * w + 16 * mi + kq * 4 + r;
            if (m < SEQ) {
                float scale = 1.f / (lacc[mi][r] * 27.712812921102035f);
                #pragma unroll
                for (int ni = 0; ni < 4; ++ni)
                    Og[base + (size_t)m * HD + 16 * ni + l15] = f2bf(oacc[mi][ni][r] * scale);
            }
        }
    }
}

// ---------------------------------------------------------------- launch
extern "C" void kernel_launch(void* const* d_in, const int* in_sizes, int n_in,
                              void* d_out, int out_size, void* d_ws, size_t ws_size,
                              hipStream_t stream)
{
    const size_t NX = (size_t)M_TOK * EMB;
    const size_t NW = (size_t)EMB * EMB;
    const size_t NB = EMB;

    uint16_t* xbf = (uint16_t*)d_ws;
    uint16_t* Wbf[4]; uint16_t* bbf[4];
    uint16_t* cur = xbf + NX;
    for (int i = 0; i < 4; ++i) { Wbf[i] = cur; cur += NW; }
    for (int i = 0; i < 4; ++i) { bbf[i] = cur; cur += NB; }
    uint16_t* Qw = cur;
    uint16_t* Kw = Qw + NX;
    uint16_t* Vw = Kw + NX;

    const size_t need_primary  = 2 * (NX + 4 * NW + 4 * NB + 3 * NX);
    const size_t need_fallback = need_primary - 2 * NX;
    if (ws_size < need_fallback) return;
    if (ws_size < need_primary) Vw = (uint16_t*)d_out;

    CvtJobs jobs;
    jobs.j[0] = { (const float*)d_in[0], xbf,    (int)(NX / 8) };
    jobs.j[1] = { (const float*)d_in[1], Wbf[0], (int)(NW / 8) };
    jobs.j[2] = { (const float*)d_in[3], Wbf[1], (int)(NW / 8) };
    jobs.j[3] = { (const float*)d_in[5], Wbf[2], (int)(NW / 8) };
    jobs.j[4] = { (const float*)d_in[7], Wbf[3], (int)(NW / 8) };
    jobs.j[5] = { (const float*)d_in[2], bbf[0], (int)(NB / 8) };
    jobs.j[6] = { (const float*)d_in[4], bbf[1], (int)(NB / 8) };
    jobs.j[7] = { (const float*)d_in[6], bbf[2], (int)(NB / 8) };
    jobs.j[8] = { (const float*)d_in[8], bbf[3], (int)(NB / 8) };
    const int total8 = (int)((NX + 4 * NW + 4 * NB) / 8);
    convert_kernel<<<(total8 + 255) / 256, 256, 0, stream>>>(jobs);

    const int MT = (M_TOK + 127) / 128;   // 99 m-tiles

    GemmPtrs qkv;
    qkv.W[0] = Wbf[0]; qkv.W[1] = Wbf[1]; qkv.W[2] = Wbf[2];
    qkv.b[0] = bbf[0]; qkv.b[1] = bbf[1]; qkv.b[2] = bbf[2];
    qkv.out[0] = Qw; qkv.out[1] = Kw; qkv.out[2] = Vw;
    const int tot1 = MT * 18;             // 6 n-tiles x 3 weight sets
    gemm_bias_nt<<<tot1, 256, 0, stream>>>(xbf, qkv, M_TOK, tot1, 18, 0);

    attn_kernel<<<dim3(BSZ * NH), 256, 0, stream>>>(Qw, Kw, Vw, Qw);

    GemmPtrs pr;
    pr.W[0] = pr.W[1] = pr.W[2] = Wbf[3];
    pr.b[0] = pr.b[1] = pr.b[2] = bbf[3];
    pr.out[0] = pr.out[1] = pr.out[2] = d_out;
    const int tot2 = MT * 6;              // 6 n-tiles
    gemm_bias_nt<<<tot2, 256, 0, stream>>>(Qw, pr, M_TOK, tot2, 6, 1);
}

// Round 12
// 245.370 us; speedup vs baseline: 1.5630x; 1.0421x over previous
//
#include <hip/hip_runtime.h>
#include <stdint.h>

#define BSZ 64
#define SEQ 197
#define EMB 768
#define NH  12
#define HD  64
#define M_TOK (BSZ*SEQ)      // 12608 token rows
#define SHD (SEQ*HD)         // 12608 elements per (b,h) head matrix

using bf16x8 = __attribute__((ext_vector_type(8))) short;
using f32x4  = __attribute__((ext_vector_type(4))) float;

__device__ __forceinline__ float bflo(uint32_t u) { return __uint_as_float(u << 16); }
__device__ __forceinline__ uint16_t f2bf(float f) {
    uint32_t u = __float_as_uint(f);
    u += 0x7fffu + ((u >> 16) & 1u);   // RNE
    return (uint16_t)(u >> 16);
}

// ---------------------------------------------------------------- convert
struct CvtJob { const float* src; uint16_t* dst; int n8; };
struct CvtJobs { CvtJob j[9]; };

__global__ __launch_bounds__(256) void convert_kernel(CvtJobs jobs)
{
    int idx = blockIdx.x * 256 + threadIdx.x;
    #pragma unroll
    for (int r = 0; r < 9; ++r) {
        const int n8 = jobs.j[r].n8;
        if (idx < n8) {
            const uint4* s4 = (const uint4*)(jobs.j[r].src + (size_t)idx * 8);
            uint4 a = s4[0], b = s4[1];
            uint4 w;
            w.x = (uint32_t)f2bf(__uint_as_float(a.x)) | ((uint32_t)f2bf(__uint_as_float(a.y)) << 16);
            w.y = (uint32_t)f2bf(__uint_as_float(a.z)) | ((uint32_t)f2bf(__uint_as_float(a.w)) << 16);
            w.z = (uint32_t)f2bf(__uint_as_float(b.x)) | ((uint32_t)f2bf(__uint_as_float(b.y)) << 16);
            w.w = (uint32_t)f2bf(__uint_as_float(b.z)) | ((uint32_t)f2bf(__uint_as_float(b.w)) << 16);
            *(uint4*)(jobs.j[r].dst + (size_t)idx * 8) = w;
            return;
        }
        idx -= n8;
    }
}

// ---------------------------------------------------------------- GEMM
struct GemmPtrs {
    const uint16_t* W[3];
    const uint16_t* b[3];
    void*           out[3];
};

// C[m][n] = sum_k A[m][k]*W[n][k] + bias[n]  (NT, bf16 in, fp32 acc)
// Round-12: BK=64, 32 KB LDS -> FOUR blocks/CU. r6-r11 conclusion: the
// per-iteration wall (exposed DMA drain + barriers) is structure-invariant;
// the only lever that has ever moved utilization is blocks/CU overlap
// (MfmaUtil ~21% at 2 blocks). 4 blocks double drain coverage; proj's 594
// blocks now fit one residency round. r11 single-buffer iter structure kept.
// XOR-8 swizzle: row stride 128B would be 16-way conflict; storing k-chunk
// kc of row rt at slot kc^(rt&7) (applied on DMA source addr; LDS dst stays
// base+lane*16) -> reader XORs with l15&7 (== row&7) -> 2-way, free.
// per_m = n-tiles(128) per m-tile: QKV 18 (z=nt/6), proj 6 (z=0).
__global__ __launch_bounds__(256, 4) void gemm_bias_nt(const uint16_t* __restrict__ A,
                                                       GemmPtrs p, int M,
                                                       int total, int per_m, int outf32)
{
    __shared__ __align__(16) uint16_t sA[128 * 64];   // 16 KB
    __shared__ __align__(16) uint16_t sB[128 * 64];   // 16 KB

    // ---- XCD swizzle: same-m-tile blocks land on one XCD ----
    const int flat  = blockIdx.x;
    const int xcd   = flat & 7;
    const int local = flat >> 3;
    const int cbk = total >> 3, r8 = total & 7;
    const int start = xcd * cbk + (xcd < r8 ? xcd : r8);
    const int wid = start + local;
    const int m_idx = wid / per_m;
    const int nt    = wid - m_idx * per_m;
    const int z     = nt / 6;            // per_m=6 -> 0
    const int n0    = (nt - z * 6) * 128;

    const uint16_t* __restrict__ W    = p.W[z];
    const uint16_t* __restrict__ bias = p.b[z];

    const int m0   = m_idx * 128;
    const int tid  = threadIdx.x;
    const int lane = tid & 63;
    const int wave = tid >> 6;
    const int wr = wave >> 1, wc = wave & 1;   // 2x2 waves: 64m x 64n each
    const int l15 = lane & 15;
    const int kq  = lane >> 4;

    // ---- staging: 1024 chunks of 16B per tile, 4/thread per matrix ----
    // chunk ch = tid + 256*q: row rt = ch>>3, k-chunk kc = ch&7.
    // source k-offset XOR-swizzled: elems (kc ^ (rt&7))*8.
    const uint16_t* apq[4];
    const uint16_t* bpq[4];
    #pragma unroll
    for (int q = 0; q < 4; ++q) {
        int ch = tid + 256 * q;
        int rt = ch >> 3, kc = ch & 7;
        int ks = (kc ^ (rt & 7)) * 8;
        int ga = m0 + rt; if (ga >= M) ga = M - 1;
        apq[q] = A + (size_t)ga * EMB + ks;
        bpq[q] = W + (size_t)(n0 + rt) * EMB + ks;
    }

    f32x4 acc[4][4] = {};

    const int NIT = EMB / 64;   // 12
    for (int it = 0; it < NIT; ++it) {
        if (it > 0) {
            asm volatile("s_waitcnt lgkmcnt(0)" ::: "memory");  // prev reads done
            __builtin_amdgcn_s_barrier();                       // before overwrite
            asm volatile("" ::: "memory");
        }
        const int k0 = it * 64;
        #pragma unroll
        for (int q = 0; q < 4; ++q) {
            int ch8 = (tid + 256 * q) * 8;
            __builtin_amdgcn_global_load_lds(
                (const __attribute__((address_space(1))) void*)(apq[q] + k0),
                (__attribute__((address_space(3))) void*)(sA + ch8), 16, 0, 0);
            __builtin_amdgcn_global_load_lds(
                (const __attribute__((address_space(1))) void*)(bpq[q] + k0),
                (__attribute__((address_space(3))) void*)(sB + ch8), 16, 0, 0);
        }
        asm volatile("s_waitcnt vmcnt(0)" ::: "memory");
        __builtin_amdgcn_s_barrier();
        asm volatile("" ::: "memory");

        #pragma unroll
        for (int s = 0; s < 2; ++s) {
            const int cs = s * 4 + kq;                      // logical k-chunk 0..7
            bf16x8 af[4], bfr[4];
            #pragma unroll
            for (int i = 0; i < 4; ++i) {
                int row = 64 * wr + 16 * i + l15;
                af[i] = *(const bf16x8*)(sA + row * 64 + ((cs ^ (l15 & 7)) * 8));
            }
            #pragma unroll
            for (int j = 0; j < 4; ++j) {
                int row = 64 * wc + 16 * j + l15;
                bfr[j] = *(const bf16x8*)(sB + row * 64 + ((cs ^ (l15 & 7)) * 8));
            }
            #pragma unroll
            for (int i = 0; i < 4; ++i)
                #pragma unroll
                for (int j = 0; j < 4; ++j)
                    acc[i][j] = __builtin_amdgcn_mfma_f32_16x16x32_bf16(af[i], bfr[j], acc[i][j], 0, 0, 0);
        }
    }

    // C/D: col = lane&15, row = (lane>>4)*4 + reg
    const int kq4 = kq * 4;
    #pragma unroll
    for (int j = 0; j < 4; ++j) {
        int n = n0 + 64 * wc + 16 * j + l15;
        float bv = bflo((uint32_t)bias[n]);
        #pragma unroll
        for (int i = 0; i < 4; ++i) {
            #pragma unroll
            for (int r = 0; r < 4; ++r) {
                int m = m0 + 64 * wr + 16 * i + kq4 + r;
                if (m < M) {
                    float v = acc[i][j][r] + bv;
                    if (outf32) ((float*)p.out[z])[(size_t)m * EMB + n] = v;
                    else        ((uint16_t*)p.out[z])[(size_t)m * EMB + n] = f2bf(v);
                }
            }
        }
    }
}

// ---------------------------------------------------------------- attention (MFMA)
#define RV 264   // sVt row stride (keys)
#define RP 72    // sP row stride
__global__ __launch_bounds__(256) void attn_kernel(const uint16_t* __restrict__ Qg,
                                                   const uint16_t* __restrict__ Kg,
                                                   const uint16_t* __restrict__ Vg,
                                                   uint16_t* __restrict__ Og)
{
    __shared__ __align__(16) uint16_t sVt[HD * RV];
    __shared__ __align__(16) uint16_t sP[4][64 * RP];

    const int bh  = blockIdx.x;
    const size_t base = (size_t)bh * SHD;
    const int tid  = threadIdx.x;
    const int lane = tid & 63;
    const int w    = tid >> 6;
    const int l15  = lane & 15;
    const int kq   = lane >> 4;
    uint16_t* sPw = sP[w];

    {
        int r = tid >> 2, t4 = tid & 3;
        for (int c = SEQ + t4; c < RV; c += 4) sVt[r * RV + c] = 0;
    }
    for (int idx = tid; idx < SHD / 8; idx += 256) {
        int key = idx >> 3, dc = idx & 7;
        uint4 v = ((const uint4*)(Vg + base))[idx];
        uint16_t e[8];
        *(uint4*)e = v;
        #pragma unroll
        for (int j = 0; j < 8; ++j) sVt[(dc * 8 + j) * RV + key] = e[j];
    }

    bf16x8 aq[4][2];
    #pragma unroll
    for (int mi = 0; mi < 4; ++mi) {
        int m = 64 * w + 16 * mi + l15; if (m >= SEQ) m = SEQ - 1;
        const uint16_t* qp = Qg + base + (size_t)m * HD + kq * 8;
        aq[mi][0] = *(const bf16x8*)(qp);
        aq[mi][1] = *(const bf16x8*)(qp + 32);
    }

    bf16x8 ones;
    #pragma unroll
    for (int j = 0; j < 8; ++j) ones[j] = (short)0x3F80;

    f32x4 oacc[4][4] = {};
    f32x4 lacc[4]    = {};

    __syncthreads();   // sVt ready

    for (int c = 0; c < 4; ++c) {
        bf16x8 bk[4][2];
        #pragma unroll
        for (int ni = 0; ni < 4; ++ni) {
            int key = 64 * c + 16 * ni + l15; if (key >= SEQ) key = SEQ - 1;
            const uint16_t* kp = Kg + base + (size_t)key * HD + kq * 8;
            bk[ni][0] = *(const bf16x8*)(kp);
            bk[ni][1] = *(const bf16x8*)(kp + 32);
        }
        #pragma unroll
        for (int mi = 0; mi < 4; ++mi) {
            #pragma unroll
            for (int ni = 0; ni < 4; ++ni) {
                f32x4 s = {};
                s = __builtin_amdgcn_mfma_f32_16x16x32_bf16(aq[mi][0], bk[ni][0], s, 0, 0, 0);
                s = __builtin_amdgcn_mfma_f32_16x16x32_bf16(aq[mi][1], bk[ni][1], s, 0, 0, 0);
                int col = 16 * ni + l15;
                int key = 64 * c + col;
                #pragma unroll
                for (int r = 0; r < 4; ++r) {
                    float pv = (key < SEQ) ? __expf(fminf(s[r], 80.f)) : 0.f;
                    sPw[(16 * mi + kq * 4 + r) * RP + col] = f2bf(pv);
                }
            }
        }

        bf16x8 bv[2][4];
        #pragma unroll
        for (int kk = 0; kk < 2; ++kk)
            #pragma unroll
            for (int ni = 0; ni < 4; ++ni)
                bv[kk][ni] = *(const bf16x8*)(sVt + (16 * ni + l15) * RV + c * 64 + kk * 32 + kq * 8);

        #pragma unroll
        for (int mi = 0; mi < 4; ++mi) {
            #pragma unroll
            for (int kk = 0; kk < 2; ++kk) {
                bf16x8 ap = *(const bf16x8*)(sPw + (16 * mi + l15) * RP + kk * 32 + kq * 8);
                lacc[mi] = __builtin_amdgcn_mfma_f32_16x16x32_bf16(ap, ones, lacc[mi], 0, 0, 0);
                #pragma unroll
                for (int ni = 0; ni < 4; ++ni)
                    oacc[mi][ni] = __builtin_amdgcn_mfma_f32_16x16x32_bf16(ap, bv[kk][ni], oacc[mi][ni], 0, 0, 0);
            }
        }
    }

    #pragma unroll
    for (int mi = 0; mi < 4; ++mi) {
        #pragma unroll
        for (int r = 0; r < 4; ++r) {
            int m = 64 * w + 16 * mi + kq * 4 + r;
            if (m < SEQ) {
                float scale = 1.f / (lacc[mi][r] * 27.712812921102035f);
                #pragma unroll
                for (int ni = 0; ni < 4; ++ni)
                    Og[base + (size_t)m * HD + 16 * ni + l15] = f2bf(oacc[mi][ni][r] * scale);
            }
        }
    }
}

// ---------------------------------------------------------------- launch
extern "C" void kernel_launch(void* const* d_in, const int* in_sizes, int n_in,
                              void* d_out, int out_size, void* d_ws, size_t ws_size,
                              hipStream_t stream)
{
    const size_t NX = (size_t)M_TOK * EMB;
    const size_t NW = (size_t)EMB * EMB;
    const size_t NB = EMB;

    uint16_t* xbf = (uint16_t*)d_ws;
    uint16_t* Wbf[4]; uint16_t* bbf[4];
    uint16_t* cur = xbf + NX;
    for (int i = 0; i < 4; ++i) { Wbf[i] = cur; cur += NW; }
    for (int i = 0; i < 4; ++i) { bbf[i] = cur; cur += NB; }
    uint16_t* Qw = cur;
    uint16_t* Kw = Qw + NX;
    uint16_t* Vw = Kw + NX;

    const size_t need_primary  = 2 * (NX + 4 * NW + 4 * NB + 3 * NX);
    const size_t need_fallback = need_primary - 2 * NX;
    if (ws_size < need_fallback) return;
    if (ws_size < need_primary) Vw = (uint16_t*)d_out;

    CvtJobs jobs;
    jobs.j[0] = { (const float*)d_in[0], xbf,    (int)(NX / 8) };
    jobs.j[1] = { (const float*)d_in[1], Wbf[0], (int)(NW / 8) };
    jobs.j[2] = { (const float*)d_in[3], Wbf[1], (int)(NW / 8) };
    jobs.j[3] = { (const float*)d_in[5], Wbf[2], (int)(NW / 8) };
    jobs.j[4] = { (const float*)d_in[7], Wbf[3], (int)(NW / 8) };
    jobs.j[5] = { (const float*)d_in[2], bbf[0], (int)(NB / 8) };
    jobs.j[6] = { (const float*)d_in[4], bbf[1], (int)(NB / 8) };
    jobs.j[7] = { (const float*)d_in[6], bbf[2], (int)(NB / 8) };
    jobs.j[8] = { (const float*)d_in[8], bbf[3], (int)(NB / 8) };
    const int total8 = (int)((NX + 4 * NW + 4 * NB) / 8);
    convert_kernel<<<(total8 + 255) / 256, 256, 0, stream>>>(jobs);

    const int MT = (M_TOK + 127) / 128;   // 99 m-tiles

    GemmPtrs qkv;
    qkv.W[0] = Wbf[0]; qkv.W[1] = Wbf[1]; qkv.W[2] = Wbf[2];
    qkv.b[0] = bbf[0]; qkv.b[1] = bbf[1]; qkv.b[2] = bbf[2];
    qkv.out[0] = Qw; qkv.out[1] = Kw; qkv.out[2] = Vw;
    const int tot1 = MT * 18;             // 6 n-tiles x 3 weight sets
    gemm_bias_nt<<<tot1, 256, 0, stream>>>(xbf, qkv, M_TOK, tot1, 18, 0);

    attn_kernel<<<dim3(BSZ * NH), 256, 0, stream>>>(Qw, Kw, Vw, Qw);

    GemmPtrs pr;
    pr.W[0] = pr.W[1] = pr.W[2] = Wbf[3];
    pr.b[0] = pr.b[1] = pr.b[2] = bbf[3];
    pr.out[0] = pr.out[1] = pr.out[2] = d_out;
    const int tot2 = MT * 6;              // 6 n-tiles
    gemm_bias_nt<<<tot2, 256, 0, stream>>>(Qw, pr, M_TOK, tot2, 6, 1);
}

// Round 13
// 234.117 us; speedup vs baseline: 1.6382x; 1.0481x over previous
//
#include <hip/hip_runtime.h>
#include <stdint.h>

#define BSZ 64
#define SEQ 197
#define EMB 768
#define NH  12
#define HD  64
#define M_TOK (BSZ*SEQ)      // 12608 token rows
#define SHD (SEQ*HD)         // 12608 elements per (b,h) head matrix

using bf16x8 = __attribute__((ext_vector_type(8))) short;
using f32x4  = __attribute__((ext_vector_type(4))) float;

__device__ __forceinline__ float bflo(uint32_t u) { return __uint_as_float(u << 16); }
__device__ __forceinline__ float bfhi(uint32_t u) { return __uint_as_float(u & 0xffff0000u); }
__device__ __forceinline__ uint16_t f2bf(float f) {
    uint32_t u = __float_as_uint(f);
    u += 0x7fffu + ((u >> 16) & 1u);   // RNE
    return (uint16_t)(u >> 16);
}

// ---------------------------------------------------------------- convert
struct CvtJob { const float* src; uint16_t* dst; int n8; };
struct CvtJobs { CvtJob j[9]; };

__global__ __launch_bounds__(256) void convert_kernel(CvtJobs jobs)
{
    int idx = blockIdx.x * 256 + threadIdx.x;
    #pragma unroll
    for (int r = 0; r < 9; ++r) {
        const int n8 = jobs.j[r].n8;
        if (idx < n8) {
            const uint4* s4 = (const uint4*)(jobs.j[r].src + (size_t)idx * 8);
            uint4 a = s4[0], b = s4[1];
            uint4 w;
            w.x = (uint32_t)f2bf(__uint_as_float(a.x)) | ((uint32_t)f2bf(__uint_as_float(a.y)) << 16);
            w.y = (uint32_t)f2bf(__uint_as_float(a.z)) | ((uint32_t)f2bf(__uint_as_float(a.w)) << 16);
            w.z = (uint32_t)f2bf(__uint_as_float(b.x)) | ((uint32_t)f2bf(__uint_as_float(b.y)) << 16);
            w.w = (uint32_t)f2bf(__uint_as_float(b.z)) | ((uint32_t)f2bf(__uint_as_float(b.w)) << 16);
            *(uint4*)(jobs.j[r].dst + (size_t)idx * 8) = w;
            return;
        }
        idx -= n8;
    }
}

// ---------------------------------------------------------------- GEMM
struct GemmPtrs {
    const uint16_t* W[3];
    const uint16_t* b[3];
    void*           out[3];
};

// C[m][n] = sum_k A[m][k]*W[n][k] + bias[n]  (NT, bf16 in, fp32 acc)
// Round-13: operand-swapped MFMA (X=W-frag, Y=A-frag) so D[col=l15]=m,
// D[row=kq*4+r]=n -> each lane's 4 regs are 4 CONSECUTIVE n at one m ->
// epilogue is one ushort4 (bf16) / float4 (fp32) store per acc tile.
// r12 counters: WRITE 130MB vs 58 ideal + FETCH +30MB = partial-line RMW
// from 64 scalar 2B stores/thread. K-loop/staging/swizzles unchanged (r12:
// BK=64, 32KB LDS, 4 blocks/CU, XOR-8 swizzle, XCD swizzle).
// per_m = n-tiles(128) per m-tile: QKV 18 (z=nt/6), proj 6 (z=0).
__global__ __launch_bounds__(256, 4) void gemm_bias_nt(const uint16_t* __restrict__ A,
                                                       GemmPtrs p, int M,
                                                       int total, int per_m, int outf32)
{
    __shared__ __align__(16) uint16_t sA[128 * 64];   // 16 KB
    __shared__ __align__(16) uint16_t sB[128 * 64];   // 16 KB

    // ---- XCD swizzle: same-m-tile blocks land on one XCD ----
    const int flat  = blockIdx.x;
    const int xcd   = flat & 7;
    const int local = flat >> 3;
    const int cbk = total >> 3, r8 = total & 7;
    const int start = xcd * cbk + (xcd < r8 ? xcd : r8);
    const int wid = start + local;
    const int m_idx = wid / per_m;
    const int nt    = wid - m_idx * per_m;
    const int z     = nt / 6;            // per_m=6 -> 0
    const int n0    = (nt - z * 6) * 128;

    const uint16_t* __restrict__ W    = p.W[z];
    const uint16_t* __restrict__ bias = p.b[z];

    const int m0   = m_idx * 128;
    const int tid  = threadIdx.x;
    const int lane = tid & 63;
    const int wave = tid >> 6;
    const int wr = wave >> 1, wc = wave & 1;   // 2x2 waves: 64m x 64n each
    const int l15 = lane & 15;
    const int kq  = lane >> 4;

    // ---- staging: 1024 chunks of 16B per tile, 4/thread per matrix ----
    const uint16_t* apq[4];
    const uint16_t* bpq[4];
    #pragma unroll
    for (int q = 0; q < 4; ++q) {
        int ch = tid + 256 * q;
        int rt = ch >> 3, kc = ch & 7;
        int ks = (kc ^ (rt & 7)) * 8;
        int ga = m0 + rt; if (ga >= M) ga = M - 1;
        apq[q] = A + (size_t)ga * EMB + ks;
        bpq[q] = W + (size_t)(n0 + rt) * EMB + ks;
    }

    f32x4 acc[4][4] = {};

    const int NIT = EMB / 64;   // 12
    for (int it = 0; it < NIT; ++it) {
        if (it > 0) {
            asm volatile("s_waitcnt lgkmcnt(0)" ::: "memory");
            __builtin_amdgcn_s_barrier();
            asm volatile("" ::: "memory");
        }
        const int k0 = it * 64;
        #pragma unroll
        for (int q = 0; q < 4; ++q) {
            int ch8 = (tid + 256 * q) * 8;
            __builtin_amdgcn_global_load_lds(
                (const __attribute__((address_space(1))) void*)(apq[q] + k0),
                (__attribute__((address_space(3))) void*)(sA + ch8), 16, 0, 0);
            __builtin_amdgcn_global_load_lds(
                (const __attribute__((address_space(1))) void*)(bpq[q] + k0),
                (__attribute__((address_space(3))) void*)(sB + ch8), 16, 0, 0);
        }
        asm volatile("s_waitcnt vmcnt(0)" ::: "memory");
        __builtin_amdgcn_s_barrier();
        asm volatile("" ::: "memory");

        #pragma unroll
        for (int s = 0; s < 2; ++s) {
            const int cs = s * 4 + kq;                      // logical k-chunk 0..7
            bf16x8 af[4], bfr[4];
            #pragma unroll
            for (int i = 0; i < 4; ++i) {
                int row = 64 * wr + 16 * i + l15;
                af[i] = *(const bf16x8*)(sA + row * 64 + ((cs ^ (l15 & 7)) * 8));
            }
            #pragma unroll
            for (int j = 0; j < 4; ++j) {
                int row = 64 * wc + 16 * j + l15;
                bfr[j] = *(const bf16x8*)(sB + row * 64 + ((cs ^ (l15 & 7)) * 8));
            }
            // swapped operands: X=bfr (n), Y=af (m) -> D[row]=n, D[col]=m
            #pragma unroll
            for (int i = 0; i < 4; ++i)
                #pragma unroll
                for (int j = 0; j < 4; ++j)
                    acc[i][j] = __builtin_amdgcn_mfma_f32_16x16x32_bf16(bfr[j], af[i], acc[i][j], 0, 0, 0);
        }
    }

    // ---- epilogue: lane (l15,kq) holds C[m=m0+64wr+16i+l15][n=nb+16j+4kq+{0..3}]
    const int nbase = n0 + 64 * wc + 4 * kq;
    #pragma unroll
    for (int i = 0; i < 4; ++i) {
        const int m = m0 + 64 * wr + 16 * i + l15;
        if (m >= M) continue;
        #pragma unroll
        for (int j = 0; j < 4; ++j) {
            const int n = nbase + 16 * j;
            uint2 bu = *(const uint2*)(bias + n);
            float b0 = bflo(bu.x), b1 = bfhi(bu.x);
            float b2 = bflo(bu.y), b3 = bfhi(bu.y);
            float v0 = acc[i][j][0] + b0;
            float v1 = acc[i][j][1] + b1;
            float v2 = acc[i][j][2] + b2;
            float v3 = acc[i][j][3] + b3;
            if (outf32) {
                float4 w; w.x = v0; w.y = v1; w.z = v2; w.w = v3;
                *(float4*)((float*)p.out[z] + (size_t)m * EMB + n) = w;
            } else {
                uint2 w;
                w.x = (uint32_t)f2bf(v0) | ((uint32_t)f2bf(v1) << 16);
                w.y = (uint32_t)f2bf(v2) | ((uint32_t)f2bf(v3) << 16);
                *(uint2*)((uint16_t*)p.out[z] + (size_t)m * EMB + n) = w;
            }
        }
    }
}

// ---------------------------------------------------------------- attention (MFMA)
#define RV 264   // sVt row stride (keys)
#define RP 72    // sP row stride
__global__ __launch_bounds__(256) void attn_kernel(const uint16_t* __restrict__ Qg,
                                                   const uint16_t* __restrict__ Kg,
                                                   const uint16_t* __restrict__ Vg,
                                                   uint16_t* __restrict__ Og)
{
    __shared__ __align__(16) uint16_t sVt[HD * RV];
    __shared__ __align__(16) uint16_t sP[4][64 * RP];

    const int bh  = blockIdx.x;
    const size_t base = (size_t)bh * SHD;
    const int tid  = threadIdx.x;
    const int lane = tid & 63;
    const int w    = tid >> 6;
    const int l15  = lane & 15;
    const int kq   = lane >> 4;
    uint16_t* sPw = sP[w];

    {
        int r = tid >> 2, t4 = tid & 3;
        for (int c = SEQ + t4; c < RV; c += 4) sVt[r * RV + c] = 0;
    }
    for (int idx = tid; idx < SHD / 8; idx += 256) {
        int key = idx >> 3, dc = idx & 7;
        uint4 v = ((const uint4*)(Vg + base))[idx];
        uint16_t e[8];
        *(uint4*)e = v;
        #pragma unroll
        for (int j = 0; j < 8; ++j) sVt[(dc * 8 + j) * RV + key] = e[j];
    }

    bf16x8 aq[4][2];
    #pragma unroll
    for (int mi = 0; mi < 4; ++mi) {
        int m = 64 * w + 16 * mi + l15; if (m >= SEQ) m = SEQ - 1;
        const uint16_t* qp = Qg + base + (size_t)m * HD + kq * 8;
        aq[mi][0] = *(const bf16x8*)(qp);
        aq[mi][1] = *(const bf16x8*)(qp + 32);
    }

    bf16x8 ones;
    #pragma unroll
    for (int j = 0; j < 8; ++j) ones[j] = (short)0x3F80;

    f32x4 oacc[4][4] = {};
    f32x4 lacc[4]    = {};

    __syncthreads();   // sVt ready

    for (int c = 0; c < 4; ++c) {
        bf16x8 bk[4][2];
        #pragma unroll
        for (int ni = 0; ni < 4; ++ni) {
            int key = 64 * c + 16 * ni + l15; if (key >= SEQ) key = SEQ - 1;
            const uint16_t* kp = Kg + base + (size_t)key * HD + kq * 8;
            bk[ni][0] = *(const bf16x8*)(kp);
            bk[ni][1] = *(const bf16x8*)(kp + 32);
        }
        #pragma unroll
        for (int mi = 0; mi < 4; ++mi) {
            #pragma unroll
            for (int ni = 0; ni < 4; ++ni) {
                f32x4 s = {};
                s = __builtin_amdgcn_mfma_f32_16x16x32_bf16(aq[mi][0], bk[ni][0], s, 0, 0, 0);
                s = __builtin_amdgcn_mfma_f32_16x16x32_bf16(aq[mi][1], bk[ni][1], s, 0, 0, 0);
                int col = 16 * ni + l15;
                int key = 64 * c + col;
                #pragma unroll
                for (int r = 0; r < 4; ++r) {
                    float pv = (key < SEQ) ? __expf(fminf(s[r], 80.f)) : 0.f;
                    sPw[(16 * mi + kq * 4 + r) * RP + col] = f2bf(pv);
                }
            }
        }

        bf16x8 bv[2][4];
        #pragma unroll
        for (int kk = 0; kk < 2; ++kk)
            #pragma unroll
            for (int ni = 0; ni < 4; ++ni)
                bv[kk][ni] = *(const bf16x8*)(sVt + (16 * ni + l15) * RV + c * 64 + kk * 32 + kq * 8);

        #pragma unroll
        for (int mi = 0; mi < 4; ++mi) {
            #pragma unroll
            for (int kk = 0; kk < 2; ++kk) {
                bf16x8 ap = *(const bf16x8*)(sPw + (16 * mi + l15) * RP + kk * 32 + kq * 8);
                lacc[mi] = __builtin_amdgcn_mfma_f32_16x16x32_bf16(ap, ones, lacc[mi], 0, 0, 0);
                #pragma unroll
                for (int ni = 0; ni < 4; ++ni)
                    oacc[mi][ni] = __builtin_amdgcn_mfma_f32_16x16x32_bf16(ap, bv[kk][ni], oacc[mi][ni], 0, 0, 0);
            }
        }
    }

    #pragma unroll
    for (int mi = 0; mi < 4; ++mi) {
        #pragma unroll
        for (int r = 0; r < 4; ++r) {
            int m = 64 * w + 16 * mi + kq * 4 + r;
            if (m < SEQ) {
                float scale = 1.f / (lacc[mi][r] * 27.712812921102035f);
                #pragma unroll
                for (int ni = 0; ni < 4; ++ni)
                    Og[base + (size_t)m * HD + 16 * ni + l15] = f2bf(oacc[mi][ni][r] * scale);
            }
        }
    }
}

// ---------------------------------------------------------------- launch
extern "C" void kernel_launch(void* const* d_in, const int* in_sizes, int n_in,
                              void* d_out, int out_size, void* d_ws, size_t ws_size,
                              hipStream_t stream)
{
    const size_t NX = (size_t)M_TOK * EMB;
    const size_t NW = (size_t)EMB * EMB;
    const size_t NB = EMB;

    uint16_t* xbf = (uint16_t*)d_ws;
    uint16_t* Wbf[4]; uint16_t* bbf[4];
    uint16_t* cur = xbf + NX;
    for (int i = 0; i < 4; ++i) { Wbf[i] = cur; cur += NW; }
    for (int i = 0; i < 4; ++i) { bbf[i] = cur; cur += NB; }
    uint16_t* Qw = cur;
    uint16_t* Kw = Qw + NX;
    uint16_t* Vw = Kw + NX;

    const size_t need_primary  = 2 * (NX + 4 * NW + 4 * NB + 3 * NX);
    const size_t need_fallback = need_primary - 2 * NX;
    if (ws_size < need_fallback) return;
    if (ws_size < need_primary) Vw = (uint16_t*)d_out;

    CvtJobs jobs;
    jobs.j[0] = { (const float*)d_in[0], xbf,    (int)(NX / 8) };
    jobs.j[1] = { (const float*)d_in[1], Wbf[0], (int)(NW / 8) };
    jobs.j[2] = { (const float*)d_in[3], Wbf[1], (int)(NW / 8) };
    jobs.j[3] = { (const float*)d_in[5], Wbf[2], (int)(NW / 8) };
    jobs.j[4] = { (const float*)d_in[7], Wbf[3], (int)(NW / 8) };
    jobs.j[5] = { (const float*)d_in[2], bbf[0], (int)(NB / 8) };
    jobs.j[6] = { (const float*)d_in[4], bbf[1], (int)(NB / 8) };
    jobs.j[7] = { (const float*)d_in[6], bbf[2], (int)(NB / 8) };
    jobs.j[8] = { (const float*)d_in[8], bbf[3], (int)(NB / 8) };
    const int total8 = (int)((NX + 4 * NW + 4 * NB) / 8);
    convert_kernel<<<(total8 + 255) / 256, 256, 0, stream>>>(jobs);

    const int MT = (M_TOK + 127) / 128;   // 99 m-tiles

    GemmPtrs qkv;
    qkv.W[0] = Wbf[0]; qkv.W[1] = Wbf[1]; qkv.W[2] = Wbf[2];
    qkv.b[0] = bbf[0]; qkv.b[1] = bbf[1]; qkv.b[2] = bbf[2];
    qkv.out[0] = Qw; qkv.out[1] = Kw; qkv.out[2] = Vw;
    const int tot1 = MT * 18;             // 6 n-tiles x 3 weight sets
    gemm_bias_nt<<<tot1, 256, 0, stream>>>(xbf, qkv, M_TOK, tot1, 18, 0);

    attn_kernel<<<dim3(BSZ * NH), 256, 0, stream>>>(Qw, Kw, Vw, Qw);

    GemmPtrs pr;
    pr.W[0] = pr.W[1] = pr.W[2] = Wbf[3];
    pr.b[0] = pr.b[1] = pr.b[2] = bbf[3];
    pr.out[0] = pr.out[1] = pr.out[2] = d_out;
    const int tot2 = MT * 6;              // 6 n-tiles
    gemm_bias_nt<<<tot2, 256, 0, stream>>>(Qw, pr, M_TOK, tot2, 6, 1);
}